// Round 1
// 539.663 us; speedup vs baseline: 1.1633x; 1.1633x over previous
//
#include <hip/hip_runtime.h>
#include <hip/hip_bf16.h>
#include <stdint.h>

// Problem constants
#define DIN   4096
#define DOUT  4096
#define RANK  16
#define NSUB  4
#define MTOT  8192            // B*S = 4*2048
#define LDK   4160            // 4096 + 64 sub-adapter cols; 4160 = 65*64
#define KTAIL 64              // NSUB*RANK
#define NV    80              // 64 sub_A rows + 4 gate rows + 12 zero pad
#define KTILES 65             // LDK / 64

typedef __attribute__((ext_vector_type(8)))  short    short8;   // 8 bf16 (4 VGPRs)
typedef __attribute__((ext_vector_type(4)))  float    floatx4;
typedef __attribute__((ext_vector_type(8)))  unsigned short ushort8;
typedef __attribute__((ext_vector_type(4)))  unsigned short ushort4v;

static __device__ __forceinline__ unsigned short f2bf(float f) {
    unsigned int u = __float_as_uint(f);
    unsigned int r = (u + 0x7FFFu + ((u >> 16) & 1u)) >> 16;   // RNE
    return (unsigned short)r;
}

static __device__ __forceinline__ void async_copy16(const unsigned short* g, unsigned short* l) {
    __builtin_amdgcn_global_load_lds(
        (const __attribute__((address_space(1))) unsigned int*)g,
        (__attribute__((address_space(3))) unsigned int*)l,
        16, 0, 0);
}

// ---------------------------------------------------------------------------
// Kernel 0: build Vc [NV][DIN] bf16: rows 0..63 = sub_A (flat [64][DIN]),
// rows 64..67 = sub_wgate, rows 68..79 = 0 (ws is poisoned 0xAA!).
// ---------------------------------------------------------------------------
__global__ __launch_bounds__(256) void build_v_kernel(
    const float* __restrict__ sub_wgate,
    const float* __restrict__ sub_A,
    unsigned short* __restrict__ Vc)
{
    const int t = threadIdx.x;
    const int row = blockIdx.x;      // 0..79
    const float* src = (row < 64) ? (sub_A + (size_t)row * DIN)
                     : (row < 68) ? (sub_wgate + (size_t)(row - 64) * DIN)
                     : nullptr;
#pragma unroll
    for (int i = 0; i < 4; ++i) {
        int c4 = t + 256 * i;          // float4 index, 0..1023
        ushort4v v;
        if (src) {
            float4 a = ((const float4*)src)[c4];
            v[0] = f2bf(a.x); v[1] = f2bf(a.y); v[2] = f2bf(a.z); v[3] = f2bf(a.w);
        } else {
            v[0] = v[1] = v[2] = v[3] = 0;
        }
        *(ushort4v*)(Vc + (size_t)row * DIN + c4 * 4) = v;
    }
}

// ---------------------------------------------------------------------------
// Kernel 1 (v2): fused build of X_cat [MTOT][LDK] bf16.
//   cols 0..4095: bf16(x)   (single HBM pass over x)
//   cols 4096+c:  2 * relu(P[tok][64+(c>>4)]) * P[tok][c],
//       where P = x_bf16 @ Vc^T via MFMA from the same LDS staging.
// (unchanged this round — isolating the GEMM rewrite)
// ---------------------------------------------------------------------------
#define BXK 256
#define LDA 264
__global__ __launch_bounds__(256) void build_x_kernel(
    const float* __restrict__ x,
    const unsigned short* __restrict__ Vc,
    unsigned short* __restrict__ Xc)
{
    __shared__ char smem[(16 + NV) * LDA * 2];           // 50688 B
    unsigned short* As = (unsigned short*)smem;          // [16][LDA]
    unsigned short* Bs = As + 16 * LDA;                  // [NV][LDA]
    float* Pp = (float*)smem;                            // [4][16][NV], reused

    const int t  = threadIdx.x;
    const int l  = t & 63;
    const int w  = t >> 6;        // wave = k-quarter
    const int m0 = blockIdx.x * 16;
    const int lane16 = l & 15;
    const int kq     = (l >> 4) * 8;

    floatx4 acc[5] = {};

    for (int cc = 0; cc < DIN; cc += BXK) {
        // stage x chunk [16][256]: fp32 -> bf16 -> LDS + global Xc (2 u8/thread)
#pragma unroll
        for (int i = 0; i < 2; ++i) {
            int u8 = t + 256 * i;        // 0..511
            int tr = u8 >> 5;            // 32 ushort8 per row
            int c8 = u8 & 31;
            const float4* src = (const float4*)(x + (size_t)(m0 + tr) * DIN + cc + c8 * 8);
            float4 a = src[0], b = src[1];
            ushort8 v;
            v[0] = f2bf(a.x); v[1] = f2bf(a.y); v[2] = f2bf(a.z); v[3] = f2bf(a.w);
            v[4] = f2bf(b.x); v[5] = f2bf(b.y); v[6] = f2bf(b.z); v[7] = f2bf(b.w);
            *(ushort8*)&As[tr * LDA + c8 * 8] = v;
            *(ushort8*)(Xc + (size_t)(m0 + tr) * LDK + cc + c8 * 8) = v;
        }
        // stage Vc chunk [80][256] (bf16, L2-resident): 10 u8/thread
#pragma unroll
        for (int i = 0; i < 10; ++i) {
            int idx = t + 256 * i;       // 0..2559
            int vr  = idx >> 5;
            int c8  = idx & 31;
            ushort8 v = *(const ushort8*)(Vc + (size_t)vr * DIN + cc + c8 * 8);
            *(ushort8*)&Bs[vr * LDA + c8 * 8] = v;
        }
        __syncthreads();

        // MFMA: wave w handles k-steps {2w, 2w+1} of the 8 in this chunk
#pragma unroll
        for (int s = 0; s < 2; ++s) {
            int ks = w * 2 + s;
            short8 af = *(const short8*)&As[lane16 * LDA + ks * 32 + kq];
#pragma unroll
            for (int n = 0; n < 5; ++n) {
                short8 bf = *(const short8*)&Bs[(n * 16 + lane16) * LDA + ks * 32 + kq];
                acc[n] = __builtin_amdgcn_mfma_f32_16x16x32_bf16(af, bf, acc[n], 0, 0, 0);
            }
        }
        __syncthreads();
    }

    // dump partial P (C/D layout: col=lane&15, row=(l>>4)*4+reg)
#pragma unroll
    for (int n = 0; n < 5; ++n)
#pragma unroll
        for (int r = 0; r < 4; ++r)
            Pp[(w * 16 + (l >> 4) * 4 + r) * NV + n * 16 + lane16] = acc[n][r];
    __syncthreads();

    // gated tail: 16 tokens x 64 cols, summing the 4 k-partials
#pragma unroll
    for (int i = 0; i < 4; ++i) {
        int v  = t + 256 * i;            // 0..1023
        int tr = v >> 6;
        int c  = v & 63;
        int j  = c >> 4;
        float ps = 0.f, gs = 0.f;
#pragma unroll
        for (int q = 0; q < 4; ++q) {
            ps += Pp[(q * 16 + tr) * NV + c];
            gs += Pp[(q * 16 + tr) * NV + 64 + j];
        }
        Xc[(size_t)(m0 + tr) * LDK + DIN + c] = f2bf(2.0f * fmaxf(gs, 0.f) * ps);
    }
}

// ---------------------------------------------------------------------------
// Kernel 2 (v2): build W_cat [DOUT][LDK] bf16 — streaming, no big LDS.
// (unchanged this round)
// ---------------------------------------------------------------------------
__global__ __launch_bounds__(256) void build_w_kernel(
    const float* __restrict__ W,        // [DOUT][DIN]
    const float* __restrict__ base_A,   // [RANK][DIN]
    const float* __restrict__ base_B,   // [DOUT][RANK]
    const float* __restrict__ sub_B,    // [NSUB][DOUT][RANK]
    unsigned short* __restrict__ Wc)
{
    __shared__ float bBs[8 * RANK];

    const int t  = threadIdx.x;
    const int o0 = (blockIdx.x >> 2) * 8;
    const int cc = (blockIdx.x & 3) * 1024;
    const int q  = (cc >> 2) + t;        // float4 index into a DIN row

    if (t < 128) bBs[t] = 2.0f * base_B[(size_t)o0 * RANK + t];
    __syncthreads();

    float4 acc[8];
#pragma unroll
    for (int o = 0; o < 8; ++o)
        acc[o] = ((const float4*)(W + (size_t)(o0 + o) * DIN))[q];

#pragma unroll
    for (int r = 0; r < RANK; ++r) {
        float4 a = ((const float4*)(base_A + (size_t)r * DIN))[q];
#pragma unroll
        for (int o = 0; o < 8; ++o) {
            float s = bBs[o * RANK + r];
            acc[o].x += s * a.x; acc[o].y += s * a.y;
            acc[o].z += s * a.z; acc[o].w += s * a.w;
        }
    }

#pragma unroll
    for (int o = 0; o < 8; ++o) {
        ushort4v v;
        v[0] = f2bf(acc[o].x); v[1] = f2bf(acc[o].y);
        v[2] = f2bf(acc[o].z); v[3] = f2bf(acc[o].w);
        *(ushort4v*)(Wc + (size_t)(o0 + o) * LDK + q * 4) = v;
    }

    // tail: one col-chunk per o-group writes the 8 x 64 sub_B cols
    if ((blockIdx.x & 3) == 0) {
#pragma unroll
        for (int i = 0; i < 2; ++i) {
            int v = t + 256 * i;             // 0..511
            int o = v >> 6;
            int c = v & 63;
            int j = c >> 4;
            int r = c & 15;
            float s = sub_B[((size_t)j * DOUT + (o0 + o)) * RANK + r];
            Wc[(size_t)(o0 + o) * LDK + DIN + c] = f2bf(s);
        }
    }
}

// ---------------------------------------------------------------------------
// Kernel 3 (v3): out[M][N] = X_cat @ W_cat^T + bias — 256x256 8-phase schedule
// (T1 XCD swizzle + T2 XOR LDS swizzle + T3/T4 counted vmcnt + T5 setprio).
// 512 threads = 8 waves (2M x 4N), each wave owns 128x64 out. BK=64, K=65 tiles.
// LDS 128 KiB: A[2][256][64] | B[2][256][64] bf16, double-buffered by tile.
//
// Staging stream (half-tiles, 2 global_load_lds x 16B per thread each):
//   tile t order [B0,B1,A0,A1]; A1(t+1) issued in phase1 of tile t (into buf^1),
//   B0/B1/A0(t+2) issued in phases 2/3/4 (into buf, over regions whose last
//   reader phase already passed a barrier). vmcnt(6) once per tile (phase 4)
//   keeps 3 half-tiles in flight; epilogue tiles drain with vmcnt(0).
//
// LDS swizzle: rows are 8 chunks of 16 B; physical chunk = logical ^ (row&7).
// global_load_lds writes linearly, so the per-lane GLOBAL source address is
// pre-swizzled (m173) and ds_reads apply the same XOR -> 2-way residual (free).
// ---------------------------------------------------------------------------
#define STAGE_A(tt, h, b) do { \
    const unsigned short* s_ = gA + (size_t)(h) * 128 * LDK + (tt) * 64; \
    unsigned short* d_ = &lds[((b) << 14) + (h) * 8192 + tid * 8]; \
    async_copy16(s_, d_); \
    async_copy16(s_ + (size_t)64 * LDK, d_ + 4096); \
} while (0)

#define STAGE_B(tt, h, b) do { \
    const unsigned short* s_ = gB + (size_t)(h) * 128 * LDK + (tt) * 64; \
    unsigned short* d_ = &lds[32768 + ((b) << 14) + (h) * 8192 + tid * 8]; \
    async_copy16(s_, d_); \
    async_copy16(s_ + (size_t)64 * LDK, d_ + 4096); \
} while (0)

#define LDA_(b, mh, i, s) (*(const short8*)&lds[((b) << 14) + \
    (wm * 128 + (mh) * 64 + (i) * 16 + lane16) * 64 + ((((s) * 4 + g) ^ lx) << 3)])
#define LDB_(b, j, s) (*(const short8*)&lds[32768 + ((b) << 14) + \
    (wn * 64 + (j) * 16 + lane16) * 64 + ((((s) * 4 + g) ^ lx) << 3)])

#define MFMA_QUAD(mh, jlo) do { \
    _Pragma("unroll") \
    for (int i_ = 0; i_ < 4; ++i_) { \
        _Pragma("unroll") \
        for (int jj_ = 0; jj_ < 2; ++jj_) { \
            acc[(mh)*4+i_][(jlo)+jj_] = __builtin_amdgcn_mfma_f32_16x16x32_bf16( \
                af[i_][0], bb[(jlo)+jj_][0], acc[(mh)*4+i_][(jlo)+jj_], 0, 0, 0); \
            acc[(mh)*4+i_][(jlo)+jj_] = __builtin_amdgcn_mfma_f32_16x16x32_bf16( \
                af[i_][1], bb[(jlo)+jj_][1], acc[(mh)*4+i_][(jlo)+jj_], 0, 0, 0); \
        } \
    } \
} while (0)

#define PH_SYNC() do { \
    __builtin_amdgcn_s_barrier(); \
    asm volatile("s_waitcnt lgkmcnt(0)" ::: "memory"); \
    __builtin_amdgcn_sched_barrier(0); \
} while (0)

__global__ __launch_bounds__(512, 2) void gemm_kernel(
    const unsigned short* __restrict__ Xc,
    const unsigned short* __restrict__ Wc,
    const float* __restrict__ bias,
    float* __restrict__ out)
{
    __shared__ unsigned short lds[65536];   // 128 KiB

    const int tid = threadIdx.x;
    const int l   = tid & 63;
    const int wv  = tid >> 6;        // 0..7
    const int wm  = wv >> 2;         // 0..1
    const int wn  = wv & 3;          // 0..3
    const int lane16 = l & 15;
    const int g   = l >> 4;          // 0..3
    const int lx  = lane16 & 7;      // swizzle key

    // XCD-aware swizzle: 512 wgs, 8 XCDs, 64 contiguous per XCD (bijective)
    const int bid   = blockIdx.x;
    const int wg    = (bid & 7) * 64 + (bid >> 3);
    const int m0    = (wg >> 4) * 256;   // 32 m-tiles
    const int n0    = (wg & 15) * 256;   // 16 n-tiles

    // staging source coords (pre-swizzled global chunk)
    const int r0 = tid >> 3;                 // 0..63
    const int c0 = (tid & 7) ^ (r0 & 7);
    const unsigned short* gA = Xc + (size_t)(m0 + r0) * LDK + c0 * 8;
    const unsigned short* gB = Wc + (size_t)(n0 + r0) * LDK + c0 * 8;

    floatx4 acc[8][4] = {};
    short8 af[4][2], bb[4][2];

    // prologue: tile0 fully + tile1 {B0,B1,A0}; 14 loads; keep last 3 halves in flight
    STAGE_B(0, 0, 0); STAGE_B(0, 1, 0); STAGE_A(0, 0, 0); STAGE_A(0, 1, 0);
    STAGE_B(1, 0, 1); STAGE_B(1, 1, 1); STAGE_A(1, 0, 1);
    asm volatile("s_waitcnt vmcnt(6)" ::: "memory");
    __builtin_amdgcn_s_barrier();

    for (int t = 0; t < KTILES; ++t) {
        const int cur = t & 1, nx = cur ^ 1;

        // ---- phase 1: quadrant (mh0, nh0); stage (t+1).A1 -> buf^1
#pragma unroll
        for (int i = 0; i < 4; ++i) { af[i][0] = LDA_(cur, 0, i, 0); af[i][1] = LDA_(cur, 0, i, 1); }
        if (wn < 2) {
#pragma unroll
            for (int j = 0; j < 4; ++j) { bb[j][0] = LDB_(cur, j, 0); bb[j][1] = LDB_(cur, j, 1); }
            // pin the cross-phase-held nh1 frags before B0 region is re-staged (ph2)
            asm volatile("" :: "v"(bb[2][0]), "v"(bb[2][1]), "v"(bb[3][0]), "v"(bb[3][1]));
        } else {
#pragma unroll
            for (int j = 0; j < 2; ++j) { bb[j][0] = LDB_(cur, j, 0); bb[j][1] = LDB_(cur, j, 1); }
        }
        if (t + 1 < KTILES) STAGE_A(t + 1, 1, nx);
        PH_SYNC();
        __builtin_amdgcn_s_setprio(1);
        MFMA_QUAD(0, 0);
        __builtin_amdgcn_s_setprio(0);
        __builtin_amdgcn_s_barrier();

        // ---- phase 2: (mh0, nh1); stage (t+2).B0 -> buf
        if (wn >= 2) {
#pragma unroll
            for (int j = 2; j < 4; ++j) { bb[j][0] = LDB_(cur, j, 0); bb[j][1] = LDB_(cur, j, 1); }
        }
        if (t + 2 < KTILES) STAGE_B(t + 2, 0, cur);
        PH_SYNC();
        __builtin_amdgcn_s_setprio(1);
        MFMA_QUAD(0, 2);
        __builtin_amdgcn_s_setprio(0);
        __builtin_amdgcn_s_barrier();

        // ---- phase 3: (mh1, nh0); stage (t+2).B1 -> buf
#pragma unroll
        for (int i = 0; i < 4; ++i) { af[i][0] = LDA_(cur, 1, i, 0); af[i][1] = LDA_(cur, 1, i, 1); }
        if (t + 2 < KTILES) STAGE_B(t + 2, 1, cur);
        PH_SYNC();
        __builtin_amdgcn_s_setprio(1);
        MFMA_QUAD(1, 0);
        __builtin_amdgcn_s_setprio(0);
        __builtin_amdgcn_s_barrier();

        // ---- phase 4: (mh1, nh1); stage (t+2).A0 -> buf; counted vmcnt
        if (t + 2 < KTILES) STAGE_A(t + 2, 0, cur);
        __builtin_amdgcn_s_barrier();
        __builtin_amdgcn_sched_barrier(0);
        __builtin_amdgcn_s_setprio(1);
        MFMA_QUAD(1, 2);
        __builtin_amdgcn_s_setprio(0);
        if (t + 2 < KTILES)      { asm volatile("s_waitcnt vmcnt(6)" ::: "memory"); }
        else if (t + 1 < KTILES) { asm volatile("s_waitcnt vmcnt(0)" ::: "memory"); }
        __builtin_amdgcn_s_barrier();
    }

    // epilogue: C/D layout col = lane&15, row = (lane>>4)*4 + reg
    const int row_l = g * 4;
#pragma unroll
    for (int j = 0; j < 4; ++j) {
        const int gcol = n0 + wn * 64 + j * 16 + lane16;
        const float bv = bias[gcol];
#pragma unroll
        for (int i = 0; i < 8; ++i) {
            const int grow = m0 + wm * 128 + i * 16 + row_l;
            size_t base = (size_t)grow * DOUT + gcol;
            out[base]            = acc[i][j][0] + bv;
            out[base + DOUT]     = acc[i][j][1] + bv;
            out[base + 2 * DOUT] = acc[i][j][2] + bv;
            out[base + 3 * DOUT] = acc[i][j][3] + bv;
        }
    }
}

// ---------------------------------------------------------------------------
extern "C" void kernel_launch(void* const* d_in, const int* in_sizes, int n_in,
                              void* d_out, int out_size, void* d_ws, size_t ws_size,
                              hipStream_t stream) {
    const float* x         = (const float*)d_in[0];
    const float* base_W    = (const float*)d_in[1];
    const float* base_b    = (const float*)d_in[2];
    const float* base_A    = (const float*)d_in[3];
    const float* base_B    = (const float*)d_in[4];
    const float* sub_wgate = (const float*)d_in[5];
    const float* sub_A     = (const float*)d_in[6];
    const float* sub_B     = (const float*)d_in[7];
    float* out = (float*)d_out;

    // workspace layout (bf16): X_cat [8192][4160], W_cat [4096][4160], Vc [80][4096]
    unsigned short* Xc = (unsigned short*)d_ws;
    unsigned short* Wc = Xc + (size_t)MTOT * LDK;
    unsigned short* Vc = Wc + (size_t)DOUT * LDK;

    build_v_kernel<<<NV, 256, 0, stream>>>(sub_wgate, sub_A, Vc);
    build_x_kernel<<<MTOT / 16, 256, 0, stream>>>(x, Vc, Xc);
    build_w_kernel<<<(DOUT / 8) * 4, 256, 0, stream>>>(base_W, base_A, base_B, sub_B, Wc);
    gemm_kernel<<<(MTOT / 256) * (DOUT / 256), 512, 0, stream>>>(Xc, Wc, base_b, out);
}

// Round 2
// 524.352 us; speedup vs baseline: 1.1973x; 1.0292x over previous
//
#include <hip/hip_runtime.h>
#include <hip/hip_bf16.h>
#include <stdint.h>

// Problem constants
#define DIN   4096
#define DOUT  4096
#define RANK  16
#define NSUB  4
#define MTOT  8192            // B*S = 4*2048
#define LDK   4160            // 4096 + 64 sub-adapter cols; 4160 = 65*64
#define KTAIL 64              // NSUB*RANK
#define NV    80              // 64 sub_A rows + 4 gate rows + 12 zero pad
#define KTILES 65             // LDK / 64

typedef __attribute__((ext_vector_type(8)))  short    short8;   // 8 bf16 (4 VGPRs)
typedef __attribute__((ext_vector_type(4)))  float    floatx4;
typedef __attribute__((ext_vector_type(8)))  unsigned short ushort8;
typedef __attribute__((ext_vector_type(4)))  unsigned short ushort4v;

static __device__ __forceinline__ unsigned short f2bf(float f) {
    unsigned int u = __float_as_uint(f);
    unsigned int r = (u + 0x7FFFu + ((u >> 16) & 1u)) >> 16;   // RNE
    return (unsigned short)r;
}

static __device__ __forceinline__ void async_copy16(const unsigned short* g, unsigned short* l) {
    __builtin_amdgcn_global_load_lds(
        (const __attribute__((address_space(1))) unsigned int*)g,
        (__attribute__((address_space(3))) unsigned int*)l,
        16, 0, 0);
}

// ---------------------------------------------------------------------------
// Kernel 0: build Vc [NV][DIN] bf16: rows 0..63 = sub_A (flat [64][DIN]),
// rows 64..67 = sub_wgate, rows 68..79 = 0 (ws is poisoned 0xAA!).
// ---------------------------------------------------------------------------
__global__ __launch_bounds__(256) void build_v_kernel(
    const float* __restrict__ sub_wgate,
    const float* __restrict__ sub_A,
    unsigned short* __restrict__ Vc)
{
    const int t = threadIdx.x;
    const int row = blockIdx.x;      // 0..79
    const float* src = (row < 64) ? (sub_A + (size_t)row * DIN)
                     : (row < 68) ? (sub_wgate + (size_t)(row - 64) * DIN)
                     : nullptr;
#pragma unroll
    for (int i = 0; i < 4; ++i) {
        int c4 = t + 256 * i;          // float4 index, 0..1023
        ushort4v v;
        if (src) {
            float4 a = ((const float4*)src)[c4];
            v[0] = f2bf(a.x); v[1] = f2bf(a.y); v[2] = f2bf(a.z); v[3] = f2bf(a.w);
        } else {
            v[0] = v[1] = v[2] = v[3] = 0;
        }
        *(ushort4v*)(Vc + (size_t)row * DIN + c4 * 4) = v;
    }
}

// ---------------------------------------------------------------------------
// Kernel 1 (v2): fused build of X_cat [MTOT][LDK] bf16.  (unchanged)
// ---------------------------------------------------------------------------
#define BXK 256
#define LDA 264
__global__ __launch_bounds__(256) void build_x_kernel(
    const float* __restrict__ x,
    const unsigned short* __restrict__ Vc,
    unsigned short* __restrict__ Xc)
{
    __shared__ char smem[(16 + NV) * LDA * 2];           // 50688 B
    unsigned short* As = (unsigned short*)smem;          // [16][LDA]
    unsigned short* Bs = As + 16 * LDA;                  // [NV][LDA]
    float* Pp = (float*)smem;                            // [4][16][NV], reused

    const int t  = threadIdx.x;
    const int l  = t & 63;
    const int w  = t >> 6;        // wave = k-quarter
    const int m0 = blockIdx.x * 16;
    const int lane16 = l & 15;
    const int kq     = (l >> 4) * 8;

    floatx4 acc[5] = {};

    for (int cc = 0; cc < DIN; cc += BXK) {
        // stage x chunk [16][256]: fp32 -> bf16 -> LDS + global Xc (2 u8/thread)
#pragma unroll
        for (int i = 0; i < 2; ++i) {
            int u8 = t + 256 * i;        // 0..511
            int tr = u8 >> 5;            // 32 ushort8 per row
            int c8 = u8 & 31;
            const float4* src = (const float4*)(x + (size_t)(m0 + tr) * DIN + cc + c8 * 8);
            float4 a = src[0], b = src[1];
            ushort8 v;
            v[0] = f2bf(a.x); v[1] = f2bf(a.y); v[2] = f2bf(a.z); v[3] = f2bf(a.w);
            v[4] = f2bf(b.x); v[5] = f2bf(b.y); v[6] = f2bf(b.z); v[7] = f2bf(b.w);
            *(ushort8*)&As[tr * LDA + c8 * 8] = v;
            *(ushort8*)(Xc + (size_t)(m0 + tr) * LDK + cc + c8 * 8) = v;
        }
        // stage Vc chunk [80][256] (bf16, L2-resident): 10 u8/thread
#pragma unroll
        for (int i = 0; i < 10; ++i) {
            int idx = t + 256 * i;       // 0..2559
            int vr  = idx >> 5;
            int c8  = idx & 31;
            ushort8 v = *(const ushort8*)(Vc + (size_t)vr * DIN + cc + c8 * 8);
            *(ushort8*)&Bs[vr * LDA + c8 * 8] = v;
        }
        __syncthreads();

        // MFMA: wave w handles k-steps {2w, 2w+1} of the 8 in this chunk
#pragma unroll
        for (int s = 0; s < 2; ++s) {
            int ks = w * 2 + s;
            short8 af = *(const short8*)&As[lane16 * LDA + ks * 32 + kq];
#pragma unroll
            for (int n = 0; n < 5; ++n) {
                short8 bf = *(const short8*)&Bs[(n * 16 + lane16) * LDA + ks * 32 + kq];
                acc[n] = __builtin_amdgcn_mfma_f32_16x16x32_bf16(af, bf, acc[n], 0, 0, 0);
            }
        }
        __syncthreads();
    }

    // dump partial P (C/D layout: col=lane&15, row=(l>>4)*4+reg)
#pragma unroll
    for (int n = 0; n < 5; ++n)
#pragma unroll
        for (int r = 0; r < 4; ++r)
            Pp[(w * 16 + (l >> 4) * 4 + r) * NV + n * 16 + lane16] = acc[n][r];
    __syncthreads();

    // gated tail: 16 tokens x 64 cols, summing the 4 k-partials
#pragma unroll
    for (int i = 0; i < 4; ++i) {
        int v  = t + 256 * i;            // 0..1023
        int tr = v >> 6;
        int c  = v & 63;
        int j  = c >> 4;
        float ps = 0.f, gs = 0.f;
#pragma unroll
        for (int q = 0; q < 4; ++q) {
            ps += Pp[(q * 16 + tr) * NV + c];
            gs += Pp[(q * 16 + tr) * NV + 64 + j];
        }
        Xc[(size_t)(m0 + tr) * LDK + DIN + c] = f2bf(2.0f * fmaxf(gs, 0.f) * ps);
    }
}

// ---------------------------------------------------------------------------
// Kernel 2 (v2): build W_cat [DOUT][LDK] bf16 — streaming.  (unchanged)
// ---------------------------------------------------------------------------
__global__ __launch_bounds__(256) void build_w_kernel(
    const float* __restrict__ W,        // [DOUT][DIN]
    const float* __restrict__ base_A,   // [RANK][DIN]
    const float* __restrict__ base_B,   // [DOUT][RANK]
    const float* __restrict__ sub_B,    // [NSUB][DOUT][RANK]
    unsigned short* __restrict__ Wc)
{
    __shared__ float bBs[8 * RANK];

    const int t  = threadIdx.x;
    const int o0 = (blockIdx.x >> 2) * 8;
    const int cc = (blockIdx.x & 3) * 1024;
    const int q  = (cc >> 2) + t;        // float4 index into a DIN row

    if (t < 128) bBs[t] = 2.0f * base_B[(size_t)o0 * RANK + t];
    __syncthreads();

    float4 acc[8];
#pragma unroll
    for (int o = 0; o < 8; ++o)
        acc[o] = ((const float4*)(W + (size_t)(o0 + o) * DIN))[q];

#pragma unroll
    for (int r = 0; r < RANK; ++r) {
        float4 a = ((const float4*)(base_A + (size_t)r * DIN))[q];
#pragma unroll
        for (int o = 0; o < 8; ++o) {
            float s = bBs[o * RANK + r];
            acc[o].x += s * a.x; acc[o].y += s * a.y;
            acc[o].z += s * a.z; acc[o].w += s * a.w;
        }
    }

#pragma unroll
    for (int o = 0; o < 8; ++o) {
        ushort4v v;
        v[0] = f2bf(acc[o].x); v[1] = f2bf(acc[o].y);
        v[2] = f2bf(acc[o].z); v[3] = f2bf(acc[o].w);
        *(ushort4v*)(Wc + (size_t)(o0 + o) * LDK + q * 4) = v;
    }

    // tail: one col-chunk per o-group writes the 8 x 64 sub_B cols
    if ((blockIdx.x & 3) == 0) {
#pragma unroll
        for (int i = 0; i < 2; ++i) {
            int v = t + 256 * i;             // 0..511
            int o = v >> 6;
            int c = v & 63;
            int j = c >> 4;
            int r = c & 15;
            float s = sub_B[((size_t)j * DOUT + (o0 + o)) * RANK + r];
            Wc[(size_t)(o0 + o) * LDK + DIN + c] = f2bf(s);
        }
    }
}

// ---------------------------------------------------------------------------
// Kernel 3 (v4): out = X_cat @ W_cat^T + bias — 256x256, BK=64, 8 waves.
// v4 changes vs v3 (same staging/swizzle invariants, verified in R1):
//   * K-loop unrolled x2 -> compile-time buffer parity; ds_reads are
//     base-VGPR + immediate-offset; staging uses 4 incrementing pointers.
//   * Barriers reduced to the 4/tile the overwrite-ordering proof needs;
//     raw s_barrier with "memory" clobber; NO forced lgkmcnt(0) -- plain C++
//     ds_reads let the compiler emit fine-grained lgkmcnt so MFMA overlaps
//     the DS unit serving remaining reads; waves drift -> DS || MFMA overlap.
//   * MFMA k-outer order: same-acc reuse separated by 8 independent MFMAs.
//   * Read balance per tile: P1 af[mh0]+bb[j01]=12, P2 bb[j23]=4, P3 af[mh1]=8.
// Region last-read vs re-stage (all barrier-separated):
//   A1(nx)  staged P1   (last read: prev tile P3, af mh1 by wm1)
//   B0,B1   staged P3top(last read: P2 bb j23; P2-close barrier separates)
//   A0      staged P3mid(last read: P3 af mh1 by wm0; P3-mid barrier separates)
// vmcnt(6) once per tile: at t.P3, the 6 newest loads {B0,B1,A0}(t+2) may be
// in flight; everything tile t+1 needs has landed before t's close barrier.
// ---------------------------------------------------------------------------
#define BARM() asm volatile("s_barrier" ::: "memory")

#define LDA_(B,MH,I,S) (*(const short8*)((const char*)lds + (B)*32768 + (MH)*8192 + (I)*2048 + (aBy ^ ((S)*64))))
#define LDB_(B,J,S)    (*(const short8*)((const char*)lds + 65536 + (B)*32768 + (J)*2048 + (bBy ^ ((S)*64))))

#define STG(P, DST) do { async_copy16((P), (DST)); \
                         async_copy16((P) + (size_t)64 * LDK, (DST) + 4096); } while (0)
#define STAGE_A0(P,B) STG((P), &lds[(B)*16384 + tid*8])
#define STAGE_A1(P,B) STG((P), &lds[(B)*16384 + 8192 + tid*8])
#define STAGE_B0(P,B) STG((P), &lds[32768 + (B)*16384 + tid*8])
#define STAGE_B1(P,B) STG((P), &lds[32768 + (B)*16384 + 8192 + tid*8])

#define MFMA_HALF(MH, JLO) do { \
    _Pragma("unroll") for (int s_ = 0; s_ < 2; ++s_) \
    _Pragma("unroll") for (int i_ = 0; i_ < 4; ++i_) \
    _Pragma("unroll") for (int jj_ = 0; jj_ < 2; ++jj_) \
        acc[(MH)*4+i_][(JLO)+jj_] = __builtin_amdgcn_mfma_f32_16x16x32_bf16( \
            af[i_][s_], bb[(JLO)+jj_][s_], acc[(MH)*4+i_][(JLO)+jj_], 0, 0, 0); \
} while (0)

#define TILE_BODY(T, CUR) do { \
    /* P1: af[mh0] (8) + bb[j0,1] (4); stage A1(T+1) -> buf CUR^1 */ \
    _Pragma("unroll") for (int i_ = 0; i_ < 4; ++i_) { \
        af[i_][0] = LDA_(CUR, 0, i_, 0); af[i_][1] = LDA_(CUR, 0, i_, 1); } \
    _Pragma("unroll") for (int j_ = 0; j_ < 2; ++j_) { \
        bb[j_][0] = LDB_(CUR, j_, 0); bb[j_][1] = LDB_(CUR, j_, 1); } \
    if ((T) + 1 < KTILES) { STAGE_A1(pA1, (CUR) ^ 1); } \
    pA1 += 64; \
    __builtin_amdgcn_s_setprio(1); MFMA_HALF(0, 0); __builtin_amdgcn_s_setprio(0); \
    BARM(); \
    /* P2: bb[j2,3] (4) */ \
    _Pragma("unroll") for (int j_ = 2; j_ < 4; ++j_) { \
        bb[j_][0] = LDB_(CUR, j_, 0); bb[j_][1] = LDB_(CUR, j_, 1); } \
    __builtin_amdgcn_s_setprio(1); MFMA_HALF(0, 2); __builtin_amdgcn_s_setprio(0); \
    BARM(); \
    /* P3: af[mh1] (8); stage B0,B1(T+2); mid-barrier; stage A0(T+2); 32 MFMA */ \
    _Pragma("unroll") for (int i_ = 0; i_ < 4; ++i_) { \
        af[i_][0] = LDA_(CUR, 1, i_, 0); af[i_][1] = LDA_(CUR, 1, i_, 1); } \
    if ((T) + 2 < KTILES) { STAGE_B0(pB0, CUR); STAGE_B1(pB1, CUR); } \
    pB0 += 64; pB1 += 64; \
    BARM(); \
    if ((T) + 2 < KTILES) { STAGE_A0(pA0, CUR); } \
    pA0 += 64; \
    __builtin_amdgcn_s_setprio(1); MFMA_HALF(1, 0); MFMA_HALF(1, 2); __builtin_amdgcn_s_setprio(0); \
    if ((T) + 2 < KTILES)      { asm volatile("s_waitcnt vmcnt(6)" ::: "memory"); } \
    else if ((T) + 1 < KTILES) { asm volatile("s_waitcnt vmcnt(0)" ::: "memory"); } \
    BARM(); \
} while (0)

__global__ __launch_bounds__(512, 2) void gemm_kernel(
    const unsigned short* __restrict__ Xc,
    const unsigned short* __restrict__ Wc,
    const float* __restrict__ bias,
    float* __restrict__ out)
{
    __shared__ unsigned short lds[65536];   // 128 KiB

    const int tid = threadIdx.x;
    const int l   = tid & 63;
    const int wv  = tid >> 6;        // 0..7
    const int wm  = wv >> 2;         // 0..1
    const int wn  = wv & 3;          // 0..3
    const int lane16 = l & 15;
    const int g   = l >> 4;          // 0..3
    const int lx  = lane16 & 7;      // swizzle key

    // XCD-aware swizzle: 512 wgs, 8 XCDs, 64 contiguous per XCD (bijective)
    const int bid = blockIdx.x;
    const int wg  = (bid & 7) * 64 + (bid >> 3);
    const int m0  = (wg >> 4) * 256;   // 32 m-tiles
    const int n0  = (wg & 15) * 256;   // 16 n-tiles

    // per-lane ds_read byte bases (s=0); s=1 flips byte bit 6 (chunk^4)
    const int aBy = wm * 16384 + lane16 * 128 + ((g ^ lx) << 4);
    const int bBy = wn * 8192  + lane16 * 128 + ((g ^ lx) << 4);

    // staging source pointers (pre-swizzled global chunk), advance 128 B/tile
    const int r0 = tid >> 3;                 // 0..63
    const int c0 = (tid & 7) ^ (r0 & 7);
    const unsigned short* pA0 = Xc + (size_t)(m0 + r0) * LDK + c0 * 8;
    const unsigned short* pA1 = pA0 + (size_t)128 * LDK;
    const unsigned short* pB0 = Wc + (size_t)(n0 + r0) * LDK + c0 * 8;
    const unsigned short* pB1 = pB0 + (size_t)128 * LDK;

    floatx4 acc[8][4] = {};
    short8 af[4][2], bb[4][2];

    // prologue: tile0 all 4 halves -> buf0; tile1 {B0,B1,A0} -> buf1
    STAGE_B0(pB0, 0); STAGE_B1(pB1, 0); STAGE_A0(pA0, 0); STAGE_A1(pA1, 0);
    STAGE_B0(pB0 + 64, 1); STAGE_B1(pB1 + 64, 1); STAGE_A0(pA0 + 64, 1);
    pA1 += 64; pB0 += 128; pB1 += 128; pA0 += 128;
    asm volatile("s_waitcnt vmcnt(6)" ::: "memory");   // tile0's 8 loads landed
    BARM();

    for (int t = 0; t < KTILES - 1; t += 2) {
        TILE_BODY(t, 0);
        TILE_BODY(t + 1, 1);
    }
    TILE_BODY(KTILES - 1, 0);   // tile 64, parity 0; no staging, no vmcnt

    // epilogue: C/D layout col = lane&15, row = (lane>>4)*4 + reg
    const int row_l = g * 4;
#pragma unroll
    for (int j = 0; j < 4; ++j) {
        const int gcol = n0 + wn * 64 + j * 16 + lane16;
        const float bv = bias[gcol];
#pragma unroll
        for (int i = 0; i < 8; ++i) {
            const int grow = m0 + wm * 128 + i * 16 + row_l;
            size_t base = (size_t)grow * DOUT + gcol;
            out[base]            = acc[i][j][0] + bv;
            out[base + DOUT]     = acc[i][j][1] + bv;
            out[base + 2 * DOUT] = acc[i][j][2] + bv;
            out[base + 3 * DOUT] = acc[i][j][3] + bv;
        }
    }
}

// ---------------------------------------------------------------------------
extern "C" void kernel_launch(void* const* d_in, const int* in_sizes, int n_in,
                              void* d_out, int out_size, void* d_ws, size_t ws_size,
                              hipStream_t stream) {
    const float* x         = (const float*)d_in[0];
    const float* base_W    = (const float*)d_in[1];
    const float* base_b    = (const float*)d_in[2];
    const float* base_A    = (const float*)d_in[3];
    const float* base_B    = (const float*)d_in[4];
    const float* sub_wgate = (const float*)d_in[5];
    const float* sub_A     = (const float*)d_in[6];
    const float* sub_B     = (const float*)d_in[7];
    float* out = (float*)d_out;

    // workspace layout (bf16): X_cat [8192][4160], W_cat [4096][4160], Vc [80][4096]
    unsigned short* Xc = (unsigned short*)d_ws;
    unsigned short* Wc = Xc + (size_t)MTOT * LDK;
    unsigned short* Vc = Wc + (size_t)DOUT * LDK;

    build_v_kernel<<<NV, 256, 0, stream>>>(sub_wgate, sub_A, Vc);
    build_x_kernel<<<MTOT / 16, 256, 0, stream>>>(x, Vc, Xc);
    build_w_kernel<<<(DOUT / 8) * 4, 256, 0, stream>>>(base_W, base_A, base_B, sub_B, Wc);
    gemm_kernel<<<dim3(DOUT / 256 * (MTOT / 256)), 512, 0, stream>>>(Xc, Wc, base_b, out);
}